// Round 6
// baseline (204.555 us; speedup 1.0000x reference)
//
#include <hip/hip_runtime.h>
#include <hip/hip_bf16.h>
#include <stdint.h>

// Problem constants
#define B_   4
#define T_   2048
#define H_   16
#define MTOT (B_ * T_)          // 8192 rows
#define NQKV 3072               // fused QKV output cols
#define QSC  0.18033688f        // 0.125 * log2(e): fold softmax scale + exp2 conversion into Q

typedef __attribute__((ext_vector_type(8))) __bf16 bf16x8;
typedef __attribute__((ext_vector_type(4))) float f32x4;
typedef __attribute__((ext_vector_type(16))) float f32x16;
typedef __attribute__((ext_vector_type(4))) float f4v;
typedef __attribute__((ext_vector_type(4))) unsigned short us4;
typedef __attribute__((ext_vector_type(8))) unsigned short us8;
typedef __attribute__((ext_vector_type(4))) unsigned int u32x4;

static __device__ __forceinline__ unsigned short f2bf(float f) {
  __hip_bfloat16 h = __float2bfloat16(f);
  return __builtin_bit_cast(unsigned short, h);
}

static __device__ __forceinline__ float fast_exp2(float x) {
#if __has_builtin(__builtin_amdgcn_exp2f)
  return __builtin_amdgcn_exp2f(x);
#else
  float r; asm("v_exp_f32 %0, %1" : "=v"(r) : "v"(x)); return r;
#endif
}

static __device__ __forceinline__ void async16(const void* g, void* l) {
  __builtin_amdgcn_global_load_lds(
      (const __attribute__((address_space(1))) void*)g,
      (__attribute__((address_space(3))) void*)l, 16, 0, 0);
}

// ---------------- fused fp32 -> bf16 convert (x4 vectorized, 1 launch) --------
__global__ __launch_bounds__(256) void cvt_all(
    const float* __restrict__ x, const float* __restrict__ Wq,
    const float* __restrict__ Wk, const float* __restrict__ Wv,
    const float* __restrict__ Wo, unsigned short* __restrict__ xb,
    unsigned short* __restrict__ wqkv, unsigned short* __restrict__ wo) {
  int i = blockIdx.x * blockDim.x + threadIdx.x;
  const float* s; unsigned short* d; int j;
  if (i < 2097152)      { s = x;  d = xb;             j = i; }
  else if (i < 2359296) { s = Wq; d = wqkv;           j = i - 2097152; }
  else if (i < 2621440) { s = Wk; d = wqkv + 1048576; j = i - 2359296; }
  else if (i < 2883584) { s = Wv; d = wqkv + 2097152; j = i - 2621440; }
  else                  { s = Wo; d = wo;             j = i - 2883584; }
  f4v v = reinterpret_cast<const f4v*>(s)[j];
  us4 o;
  o.x = f2bf(v.x); o.y = f2bf(v.y); o.z = f2bf(v.z); o.w = f2bf(v.w);
  reinterpret_cast<us4*>(d)[j] = o;
}

// ---------------- bf16 GEMM (m97 structure), C = A * B^T ----------------------
// Operand-SWAPPED MFMA: mfma(bfr, af) puts col=lr -> C-row, row=(lg*4+r) ->
// C-col, so each thread holds 4 CONSECUTIVE output cols of one row per frag
// -> vectorized epilogue (8B bf16-pack stores / 16B f32 stores), replacing the
// 64 scalar stores that cost ~1/3 of kernel time at K=1024.
// MODE 0: bf16 output, cols < 1024 (Q) scaled by QSC.  MODE 1: f32 output + bias.
template <int MODE>
__global__ __launch_bounds__(256) void gemm_bt(
    const unsigned short* __restrict__ A,   // [M][K] bf16 bits
    const unsigned short* __restrict__ Bw,  // [N][K] bf16 bits
    unsigned short* __restrict__ Cb,        // bf16 out (MODE 0)
    float* __restrict__ Cf,                 // f32 out (MODE 1)
    const float* __restrict__ bias,         // MODE 1
    int K, int N) {
  __shared__ __align__(16) unsigned short As[128 * 32];
  __shared__ __align__(16) unsigned short Bs[128 * 32];

  const int t = threadIdx.x;
  const int lane = t & 63;
  const int w = t >> 6;
  const int lr = lane & 15;
  const int lg = lane >> 4;
  const int wm = w >> 1;
  const int wn = w & 1;
  const int m0 = blockIdx.y * 128;
  const int n0 = blockIdx.x * 128;

  f32x4 acc[4][4];
#pragma unroll
  for (int i = 0; i < 4; ++i)
#pragma unroll
    for (int j = 0; j < 4; ++j) acc[i][j] = (f32x4){0.f, 0.f, 0.f, 0.f};

  const int srow = t >> 2;          // 0..63
  const int scol = (t & 3) * 8;     // 0,8,16,24 elems
  const unsigned short* ga = A + (size_t)(m0 + srow) * K + scol;
  const unsigned short* gb = Bw + (size_t)(n0 + srow) * K + scol;

  for (int k0 = 0; k0 < K; k0 += 32) {
    async16(ga + k0,                  &As[t * 8]);
    async16(ga + k0 + (size_t)64 * K, &As[2048 + t * 8]);
    async16(gb + k0,                  &Bs[t * 8]);
    async16(gb + k0 + (size_t)64 * K, &Bs[2048 + t * 8]);
    __syncthreads();

    bf16x8 af[4], bfr[4];
#pragma unroll
    for (int mi = 0; mi < 4; ++mi)
      af[mi] = *(const bf16x8*)&As[(wm * 64 + mi * 16 + lr) * 32 + lg * 8];
#pragma unroll
    for (int ni = 0; ni < 4; ++ni)
      bfr[ni] = *(const bf16x8*)&Bs[(wn * 64 + ni * 16 + lr) * 32 + lg * 8];
#pragma unroll
    for (int mi = 0; mi < 4; ++mi)
#pragma unroll
      for (int ni = 0; ni < 4; ++ni)
        acc[mi][ni] = __builtin_amdgcn_mfma_f32_16x16x32_bf16(
            bfr[ni], af[mi], acc[mi][ni], 0, 0, 0);   // SWAPPED -> C^T frags
    __syncthreads();
  }

  // epilogue (swapped layout): acc[mi][ni][r] = C[m0+wm*64+mi*16+lr]
  //                                             [n0+wn*64+ni*16+lg*4+r]
#pragma unroll
  for (int mi = 0; mi < 4; ++mi) {
    const int row = m0 + wm * 64 + mi * 16 + lr;
#pragma unroll
    for (int ni = 0; ni < 4; ++ni) {
      const int colb = n0 + wn * 64 + ni * 16 + lg * 4;
      if (MODE == 1) {
        f4v bv = *(const f4v*)&bias[colb];
        f4v ov;
#pragma unroll
        for (int r = 0; r < 4; ++r) ov[r] = acc[mi][ni][r] + bv[r];
        *(f4v*)&Cf[(size_t)row * N + colb] = ov;
      } else {
        const float sc = (colb < 1024) ? QSC : 1.0f;  // 1024-boundary is 4-aligned
        uint32_t u0, u1;
        float v0 = acc[mi][ni][0] * sc, v1 = acc[mi][ni][1] * sc;
        float v2 = acc[mi][ni][2] * sc, v3 = acc[mi][ni][3] * sc;
        asm("v_cvt_pk_bf16_f32 %0, %1, %2" : "=v"(u0) : "v"(v0), "v"(v1));
        asm("v_cvt_pk_bf16_f32 %0, %1, %2" : "=v"(u1) : "v"(v2), "v"(v3));
        uint2 pk = {u0, u1};
        *(uint2*)&Cb[(size_t)row * N + colb] = pk;
      }
    }
  }
}

// ---------------- causal flash attention (8 waves x 32 q-rows, 32x32 MFMA) ----
// qkv: [8192][3072] bf16 (cols: 0..1023 Q (pre-scaled), 1024..2047 K, 2048..3071 V)
// ob : [8192][1024] bf16 attention output (col = h*64+d)
__global__ __launch_bounds__(512, 2) void attn_kernel(
    const unsigned short* __restrict__ qkv, unsigned short* __restrict__ ob) {
  const int bid = blockIdx.x;
  const int qg = (bid < 256) ? (7 - (bid >> 6)) : ((bid - 256) >> 6);
  const int pair = bid & 63;
  const int b = pair >> 4;
  const int h = pair & 15;
  const int t = threadIdx.x;
  const int w = t >> 6;
  const int lane = t & 63;
  const int l31 = lane & 31;
  const int hi = lane >> 5;

  const int q0w = qg * 256 + w * 32;
  const int myBound = qg * 4 + (w >> 1);
  const int NT2 = qg * 2 + 2;

  __shared__ __align__(16) unsigned short Ks[2][128 * 64];
  __shared__ __align__(16) unsigned short Vs[2][128 * 64];

  const size_t rowbase = (size_t)(b * T_) * NQKV;

  bf16x8 Qf[4];
  {
    const unsigned short* qp =
        qkv + rowbase + (size_t)(q0w + l31) * NQKV + h * 64 + hi * 8;
#pragma unroll
    for (int m = 0; m < 4; ++m) Qf[m] = *(const bf16x8*)(qp + m * 16);
  }

  const int krow = t >> 3;
  const int kg = (t & 7) ^ (krow & 7);
  const unsigned short* kbase =
      qkv + rowbase + 1024 + h * 64 + kg * 8 + (size_t)krow * NQKV;
  const int kvr = t >> 3;
  const int dc = t & 7;
  const unsigned short* vbase =
      qkv + rowbase + 2048 + h * 64 + dc * 8 + (size_t)kvr * NQKV;

  float m_i = -INFINITY, l_i = 0.f;
  f32x16 o[2];
#pragma unroll
  for (int r = 0; r < 16; ++r) { o[0][r] = 0.f; o[1][r] = 0.f; }

#define VSCATTER(Vb, v0, v1)                                     \
  {                                                              \
    _Pragma("unroll") for (int i = 0; i < 8; ++i) {              \
      const int sw = dc ^ i;                                     \
      const int c0 = (kvr >> 3) ^ sw;                            \
      unsigned short* vp = (Vb) + (dc * 8 + i) * 128 + (kvr & 7);\
      vp[c0 * 8] = (v0)[i];                                      \
      vp[c0 * 8 + 64] = (v1)[i];                                 \
    }                                                            \
  }

  {
    async16(kbase, &Ks[0][t * 8]);
    async16(kbase + (size_t)64 * NQKV, &Ks[0][4096 + t * 8]);
    us8 v0 = *(const us8*)vbase;
    us8 v1 = *(const us8*)(vbase + (size_t)64 * NQKV);
    VSCATTER(&Vs[0][0], v0, v1);
  }

  int cur = 0;
  for (int kt = 0; kt < NT2; ++kt) {
    __syncthreads();

    const bool pf = (kt + 1 < NT2);
    us8 v0, v1;
    if (pf) {
      const size_t off = (size_t)(kt + 1) * 128 * NQKV;
      async16(kbase + off, &Ks[cur ^ 1][t * 8]);
      async16(kbase + off + (size_t)64 * NQKV, &Ks[cur ^ 1][4096 + t * 8]);
      v0 = *(const us8*)(vbase + off);
      v1 = *(const us8*)(vbase + off + (size_t)64 * NQKV);
    }

    const unsigned short* Kb = Ks[cur];
    const unsigned short* Vb = Vs[cur];

#pragma unroll
    for (int kh = 0; kh < 2; ++kh) {
      const int kt64 = kt * 2 + kh;
      if (kt64 > myBound) break;

      f32x16 a0, a1;
#pragma unroll
      for (int r = 0; r < 16; ++r) { a0[r] = 0.f; a1[r] = 0.f; }
      {
        const int rb0 = (kh * 64 + l31) * 64;
        const int rb1 = (kh * 64 + 32 + l31) * 64;
        const int r7 = l31 & 7;
        __builtin_amdgcn_s_setprio(1);
#pragma unroll
        for (int m = 0; m < 4; ++m) {
          const int c = (((m << 1) | hi) ^ r7) * 8;
          bf16x8 kf0 = *(const bf16x8*)&Kb[rb0 + c];
          bf16x8 kf1 = *(const bf16x8*)&Kb[rb1 + c];
          a0 = __builtin_amdgcn_mfma_f32_32x32x16_bf16(kf0, Qf[m], a0, 0, 0, 0);
          a1 = __builtin_amdgcn_mfma_f32_32x32x16_bf16(kf1, Qf[m], a1, 0, 0, 0);
        }
        __builtin_amdgcn_s_setprio(0);
      }

      if (kt64 == myBound) {
        const int qglob = q0w + l31;
#pragma unroll
        for (int r = 0; r < 16; ++r) {
          const int kvb = kt64 * 64 + (r & 3) + ((r >> 2) << 3) + (hi << 2);
          if (kvb > qglob) a0[r] = -INFINITY;
          if (kvb + 32 > qglob) a1[r] = -INFINITY;
        }
      }

      // online softmax: tree max, defer-max (THR=8 in log2 space)
      float m8[8];
#pragma unroll
      for (int j = 0; j < 8; ++j)
        m8[j] = fmaxf(fmaxf(a0[j], a0[j + 8]), fmaxf(a1[j], a1[j + 8]));
      float pmax = fmaxf(fmaxf(fmaxf(m8[0], m8[4]), fmaxf(m8[1], m8[5])),
                         fmaxf(fmaxf(m8[2], m8[6]), fmaxf(m8[3], m8[7])));
      pmax = fmaxf(pmax, __shfl_xor(pmax, 32));
      if (__any(pmax > m_i + 8.f)) {
        const float mnew = fmaxf(m_i, pmax);
        const float al = fast_exp2(m_i - mnew);
        m_i = mnew;
        l_i *= al;
#pragma unroll
        for (int r = 0; r < 16; ++r) { o[0][r] *= al; o[1][r] *= al; }
      }

#pragma unroll
      for (int r = 0; r < 16; ++r) {
        a0[r] = fast_exp2(a0[r] - m_i);
        a1[r] = fast_exp2(a1[r] - m_i);
      }
      float s8[8];
#pragma unroll
      for (int j = 0; j < 8; ++j)
        s8[j] = (a0[j] + a0[j + 8]) + (a1[j] + a1[j + 8]);
      float rs = ((s8[0] + s8[1]) + (s8[2] + s8[3])) +
                 ((s8[4] + s8[5]) + (s8[6] + s8[7]));
      rs += __shfl_xor(rs, 32);
      l_i += rs;

      bf16x8 Pf[4];
#pragma unroll
      for (int m = 0; m < 4; ++m) {
        const int rb2 = (m & 1) * 8;
        uint32_t u0, u1, u2, u3;
        const f32x16& s = (m >> 1) ? a1 : a0;
        asm("v_cvt_pk_bf16_f32 %0, %1, %2" : "=v"(u0) : "v"(s[rb2 + 0]), "v"(s[rb2 + 1]));
        asm("v_cvt_pk_bf16_f32 %0, %1, %2" : "=v"(u1) : "v"(s[rb2 + 2]), "v"(s[rb2 + 3]));
        asm("v_cvt_pk_bf16_f32 %0, %1, %2" : "=v"(u2) : "v"(s[rb2 + 4]), "v"(s[rb2 + 5]));
        asm("v_cvt_pk_bf16_f32 %0, %1, %2" : "=v"(u3) : "v"(s[rb2 + 6]), "v"(s[rb2 + 7]));
        asm("v_permlane32_swap_b32 %0, %1" : "+v"(u0), "+v"(u2));
        asm("v_permlane32_swap_b32 %0, %1" : "+v"(u1), "+v"(u3));
        u32x4 pw = {u0, u1, u2, u3};
        Pf[m] = __builtin_bit_cast(bf16x8, pw);
      }

      __builtin_amdgcn_s_setprio(1);
#pragma unroll
      for (int dt = 0; dt < 2; ++dt) {
        const int d = dt * 32 + l31;
        const int base = d * 128 + kh * 64;
        const int dsw = ((d >> 3) ^ d) & 7;
#pragma unroll
        for (int m = 0; m < 4; ++m) {
          bf16x8 vf = *(const bf16x8*)&Vb[base + ((((m << 1) | hi) ^ dsw) & 7) * 8];
          o[dt] = __builtin_amdgcn_mfma_f32_32x32x16_bf16(vf, Pf[m], o[dt], 0, 0, 0);
        }
      }
      __builtin_amdgcn_s_setprio(0);
    }

    if (pf) VSCATTER(&Vs[cur ^ 1][0], v0, v1);
    cur ^= 1;
  }

  const float rl = 1.0f / l_i;
#pragma unroll
  for (int dt = 0; dt < 2; ++dt) {
    float s[16];
#pragma unroll
    for (int r = 0; r < 16; ++r) s[r] = o[dt][r] * rl;
    uint32_t u[8];
#pragma unroll
    for (int p = 0; p < 8; ++p)
      asm("v_cvt_pk_bf16_f32 %0, %1, %2" : "=v"(u[p]) : "v"(s[2 * p]), "v"(s[2 * p + 1]));
    asm("v_permlane32_swap_b32 %0, %1" : "+v"(u[0]), "+v"(u[2]));
    asm("v_permlane32_swap_b32 %0, %1" : "+v"(u[1]), "+v"(u[3]));
    asm("v_permlane32_swap_b32 %0, %1" : "+v"(u[4]), "+v"(u[6]));
    asm("v_permlane32_swap_b32 %0, %1" : "+v"(u[5]), "+v"(u[7]));
    unsigned short* op =
        ob + (size_t)(b * T_ + q0w + l31) * 1024 + h * 64 + dt * 32 + hi * 8;
    u32x4 c0 = {u[0], u[1], u[2], u[3]};
    u32x4 c1 = {u[4], u[5], u[6], u[7]};
    *(u32x4*)op = c0;
    *(u32x4*)(op + 16) = c1;
  }
}

// ---------------- host launch ----------------
extern "C" void kernel_launch(void* const* d_in, const int* in_sizes, int n_in,
                              void* d_out, int out_size, void* d_ws,
                              size_t ws_size, hipStream_t stream) {
  const float* x = (const float*)d_in[0];
  const float* Wq = (const float*)d_in[1];
  const float* Wk = (const float*)d_in[2];
  const float* Wv = (const float*)d_in[3];
  const float* Wo = (const float*)d_in[4];
  const float* bo = (const float*)d_in[5];
  float* out = (float*)d_out;

  char* ws = (char*)d_ws;
  unsigned short* xb   = (unsigned short*)(ws + 0);          // 16 MB
  unsigned short* wqkv = (unsigned short*)(ws + 16777216);   // 6 MB
  unsigned short* wo   = (unsigned short*)(ws + 23068672);   // 2 MB
  unsigned short* qkv  = (unsigned short*)(ws + 25165824);   // 48 MB
  unsigned short* ob   = (unsigned short*)(ws + 75497472);   // 16 MB
  if (ws_size < 92274688u) return;

  cvt_all<<<12288, 256, 0, stream>>>(x, Wq, Wk, Wv, Wo, xb, wqkv, wo);

  // fused QKV projection (m97 structure + vectorized swapped epilogue)
  gemm_bt<0><<<dim3(NQKV / 128, MTOT / 128), 256, 0, stream>>>(
      xb, wqkv, qkv, nullptr, nullptr, 1024, NQKV);

  // causal flash attention (balanced block pairing)
  attn_kernel<<<dim3(512), 512, 0, stream>>>(qkv, ob);

  // output projection + bias
  gemm_bt<1><<<dim3(1024 / 128, MTOT / 128), 256, 0, stream>>>(
      ob, wo, nullptr, out, bo, 1024, 1024);
}

// Round 7
// 184.411 us; speedup vs baseline: 1.1092x; 1.1092x over previous
//
#include <hip/hip_runtime.h>
#include <hip/hip_bf16.h>
#include <stdint.h>

// Problem constants
#define B_   4
#define T_   2048
#define H_   16
#define MTOT (B_ * T_)          // 8192 rows
#define NQKV 3072               // fused QKV output cols
#define QSC  0.18033688f        // 0.125 * log2(e): fold softmax scale + exp2 conversion into Q

typedef __attribute__((ext_vector_type(8))) __bf16 bf16x8;
typedef __attribute__((ext_vector_type(4))) float f32x4;
typedef __attribute__((ext_vector_type(16))) float f32x16;
typedef __attribute__((ext_vector_type(4))) float f4v;
typedef __attribute__((ext_vector_type(4))) unsigned short us4;
typedef __attribute__((ext_vector_type(8))) unsigned short us8;
typedef __attribute__((ext_vector_type(4))) unsigned int u32x4;

static __device__ __forceinline__ unsigned short f2bf(float f) {
  __hip_bfloat16 h = __float2bfloat16(f);
  return __builtin_bit_cast(unsigned short, h);
}

static __device__ __forceinline__ float fast_exp2(float x) {
#if __has_builtin(__builtin_amdgcn_exp2f)
  return __builtin_amdgcn_exp2f(x);
#else
  float r; asm("v_exp_f32 %0, %1" : "=v"(r) : "v"(x)); return r;
#endif
}

static __device__ __forceinline__ void async16(const void* g, void* l) {
  __builtin_amdgcn_global_load_lds(
      (const __attribute__((address_space(1))) void*)g,
      (__attribute__((address_space(3))) void*)l, 16, 0, 0);
}

// cross-half (lane ^ 32) reduce via permlane32_swap (VALU) instead of
// ds_bpermute (__shfl_xor): t1/t2 are forced-distinct copies; after the swap
// t1 = {x.lo, x.lo}, t2 = {x.hi, x.hi} -> op(t1,t2) = full 64-lane combine.
#define XHALF(res, x, OP)                                  \
  {                                                        \
    float t1_ = (x), t2_ = (x);                            \
    asm("" : "+v"(t2_));                                   \
    asm("v_permlane32_swap_b32 %0, %1" : "+v"(t1_), "+v"(t2_)); \
    res = OP(t1_, t2_);                                    \
  }
static __device__ __forceinline__ float fadd_(float a, float b) { return a + b; }

// ---------------- fused fp32 -> bf16 convert (x4 vectorized, 1 launch) --------
__global__ __launch_bounds__(256) void cvt_all(
    const float* __restrict__ x, const float* __restrict__ Wq,
    const float* __restrict__ Wk, const float* __restrict__ Wv,
    const float* __restrict__ Wo, unsigned short* __restrict__ xb,
    unsigned short* __restrict__ wqkv, unsigned short* __restrict__ wo) {
  int i = blockIdx.x * blockDim.x + threadIdx.x;
  const float* s; unsigned short* d; int j;
  if (i < 2097152)      { s = x;  d = xb;             j = i; }
  else if (i < 2359296) { s = Wq; d = wqkv;           j = i - 2097152; }
  else if (i < 2621440) { s = Wk; d = wqkv + 1048576; j = i - 2359296; }
  else if (i < 2883584) { s = Wv; d = wqkv + 2097152; j = i - 2621440; }
  else                  { s = Wo; d = wo;             j = i - 2883584; }
  f4v v = reinterpret_cast<const f4v*>(s)[j];
  us4 o;
  o.x = f2bf(v.x); o.y = f2bf(v.y); o.z = f2bf(v.z); o.w = f2bf(v.w);
  reinterpret_cast<us4*>(d)[j] = o;
}

// ---------------- bf16 GEMM (m97 structure), C = A * B^T ----------------------
// MODE 0: bf16 output, cols < 1024 (Q) scaled by QSC.  MODE 1: f32 output + bias.
template <int MODE>
__global__ __launch_bounds__(256) void gemm_bt(
    const unsigned short* __restrict__ A,   // [M][K] bf16 bits
    const unsigned short* __restrict__ Bw,  // [N][K] bf16 bits
    unsigned short* __restrict__ Cb,        // bf16 out (MODE 0)
    float* __restrict__ Cf,                 // f32 out (MODE 1)
    const float* __restrict__ bias,         // MODE 1
    int K, int N) {
  __shared__ __align__(16) unsigned short As[128 * 32];
  __shared__ __align__(16) unsigned short Bs[128 * 32];

  const int t = threadIdx.x;
  const int lane = t & 63;
  const int w = t >> 6;
  const int lr = lane & 15;
  const int lg = lane >> 4;
  const int wm = w >> 1;
  const int wn = w & 1;
  const int m0 = blockIdx.y * 128;
  const int n0 = blockIdx.x * 128;

  f32x4 acc[4][4];
#pragma unroll
  for (int i = 0; i < 4; ++i)
#pragma unroll
    for (int j = 0; j < 4; ++j) acc[i][j] = (f32x4){0.f, 0.f, 0.f, 0.f};

  const int srow = t >> 2;          // 0..63
  const int scol = (t & 3) * 8;     // 0,8,16,24 elems
  const unsigned short* ga = A + (size_t)(m0 + srow) * K + scol;
  const unsigned short* gb = Bw + (size_t)(n0 + srow) * K + scol;

  for (int k0 = 0; k0 < K; k0 += 32) {
    async16(ga + k0,                  &As[t * 8]);
    async16(ga + k0 + (size_t)64 * K, &As[2048 + t * 8]);
    async16(gb + k0,                  &Bs[t * 8]);
    async16(gb + k0 + (size_t)64 * K, &Bs[2048 + t * 8]);
    __syncthreads();

    bf16x8 af[4], bfr[4];
#pragma unroll
    for (int mi = 0; mi < 4; ++mi)
      af[mi] = *(const bf16x8*)&As[(wm * 64 + mi * 16 + lr) * 32 + lg * 8];
#pragma unroll
    for (int ni = 0; ni < 4; ++ni)
      bfr[ni] = *(const bf16x8*)&Bs[(wn * 64 + ni * 16 + lr) * 32 + lg * 8];
#pragma unroll
    for (int mi = 0; mi < 4; ++mi)
#pragma unroll
      for (int ni = 0; ni < 4; ++ni)
        acc[mi][ni] = __builtin_amdgcn_mfma_f32_16x16x32_bf16(
            af[mi], bfr[ni], acc[mi][ni], 0, 0, 0);
    __syncthreads();
  }

  // epilogue: D layout col=lane&15, row=(lane>>4)*4+r
#pragma unroll
  for (int mi = 0; mi < 4; ++mi) {
    const int row = m0 + wm * 64 + mi * 16 + lg * 4;
#pragma unroll
    for (int ni = 0; ni < 4; ++ni) {
      const int col = n0 + wn * 64 + ni * 16 + lr;
#pragma unroll
      for (int r = 0; r < 4; ++r) {
        if (MODE == 1) {
          Cf[(size_t)(row + r) * N + col] = acc[mi][ni][r] + bias[col];
        } else {
          float v = acc[mi][ni][r];
          if (col < 1024) v *= QSC;   // pre-scale Q for exp2-space softmax
          Cb[(size_t)(row + r) * N + col] = f2bf(v);
        }
      }
    }
  }
}

// ---------------- causal flash attention (4 waves x 32 q-rows, 32x32 MFMA) ----
// qkv: [8192][3072] bf16 (cols: 0..1023 Q (pre-scaled), 1024..2047 K, 2048..3071 V)
// ob : [8192][1024] bf16 attention output (col = h*64+d)
//
// 1024 blocks = 64 (b,h) pairs x 16 q-groups of 128 rows; 4 waves x 32 q-rows.
// KVBLK=64, 32KB LDS -> 4 blocks/CU co-resident; snake qg mapping makes
// per-CU work constant. Swapped-operand S^T = K.Q^T, in-register softmax
// (tree max, defer-max THR=8, raw v_exp, permlane cross-half reduce),
// P via cvt_pk + permlane32_swap, O^T = V^T.P^T.
__global__ __launch_bounds__(256, 4) void attn_kernel(
    const unsigned short* __restrict__ qkv, unsigned short* __restrict__ ob) {
  const int bid = blockIdx.x;
  const int pair = bid & 63;
  const int g = bid >> 6;               // 0..15, dispatch round-major
  const int rnd = g >> 2, idx = g & 3;
  const int qg = (rnd == 0) ? (15 - idx)
               : (rnd == 1) ? (8 + idx)
               : (rnd == 2) ? (7 - idx) : idx;   // CU sums constant
  const int b = pair >> 4;
  const int h = pair & 15;
  const int t = threadIdx.x;
  const int w = t >> 6;                 // 0..3
  const int lane = t & 63;
  const int l31 = lane & 31;
  const int hi = lane >> 5;

  const int q0w = qg * 128 + w * 32;       // wave's q strip
  const int myBound = 2 * qg + (w >> 1);   // last kv-tile this wave computes
  const int NT = 2 * qg + 2;               // 64-row kv tiles staged by block

  __shared__ __align__(16) unsigned short Ks[2][64 * 64];
  __shared__ __align__(16) unsigned short Vs[2][64 * 64];   // V^T [d][kv], swizzled

  const size_t rowbase = (size_t)(b * T_) * NQKV;

  // ---- Q B-fragments: col=q=l31, k=d = m*16 + hi*8 + i ----
  bf16x8 Qf[4];
  {
    const unsigned short* qp =
        qkv + rowbase + (size_t)(q0w + l31) * NQKV + h * 64 + hi * 8;
#pragma unroll
    for (int m = 0; m < 4; ++m) Qf[m] = *(const bf16x8*)(qp + m * 16);
  }

  // ---- staging geometry (256 threads) ----
  // K: 2 async16/thread; call j stages rows [j*32, j*32+32). LDS chunk (row<<3)|s
  // holds global d-chunk s ^ (row&7)  (XOR swizzle, conflict-free ds_read_b128).
  const int kr = t >> 3;                // 0..31
  const int ks = t & 7;
  const unsigned short* kbase =
      qkv + rowbase + 1024 + h * 64 + (ks ^ (kr & 7)) * 8 + (size_t)kr * NQKV;
  // V: thread loads row kvr, d-chunks dc2, dc2+1; scatter-transpose:
  // elem(d,kv) -> Vs[d*64 + (((kv>>3) ^ (d>>3) ^ (d&7))&7)*8 + (kv&7)]
  const int kvr = t >> 2;               // 0..63
  const int dc2 = (t & 3) * 2;
  const unsigned short* vbase =
      qkv + rowbase + 2048 + h * 64 + dc2 * 8 + (size_t)kvr * NQKV;

  float m_i = -INFINITY, l_i = 0.f;
  f32x16 o[2];
#pragma unroll
  for (int r = 0; r < 16; ++r) { o[0][r] = 0.f; o[1][r] = 0.f; }

#define VSCATTER(Vb, v0, v1)                                       \
  {                                                                \
    _Pragma("unroll") for (int i = 0; i < 8; ++i) {                \
      const int s0 = ((kvr >> 3) ^ dc2 ^ i) & 7;                   \
      const int s1 = ((kvr >> 3) ^ (dc2 + 1) ^ i) & 7;             \
      (Vb)[(dc2 * 8 + i) * 64 + s0 * 8 + (kvr & 7)] = (v0)[i];     \
      (Vb)[((dc2 + 1) * 8 + i) * 64 + s1 * 8 + (kvr & 7)] = (v1)[i]; \
    }                                                              \
  }

  // ---- prologue: stage tile 0 into buffer 0 ----
  {
    async16(kbase, &Ks[0][t * 8]);
    async16(kbase + (size_t)32 * NQKV, &Ks[0][2048 + t * 8]);
    us8 v0 = *(const us8*)vbase;
    us8 v1 = *(const us8*)(vbase + 8);
    VSCATTER(&Vs[0][0], v0, v1);
  }

  int cur = 0;
  for (int kt = 0; kt < NT; ++kt) {
    __syncthreads();  // buf[cur] ready (drains async K + V ds_writes)

    const bool pf = (kt + 1 < NT);
    us8 v0, v1;
    if (pf) {
      const size_t off = (size_t)(kt + 1) * 64 * NQKV;
      async16(kbase + off, &Ks[cur ^ 1][t * 8]);
      async16(kbase + off + (size_t)32 * NQKV, &Ks[cur ^ 1][2048 + t * 8]);
      v0 = *(const us8*)(vbase + off);
      v1 = *(const us8*)(vbase + off + 8);
    }

    if (kt <= myBound) {
      const unsigned short* Kb = Ks[cur];
      const unsigned short* Vb = Vs[cur];

      // ---- S^T[kv][q] : 2 kv-subtiles of 32 ----
      f32x16 a0, a1;
#pragma unroll
      for (int r = 0; r < 16; ++r) { a0[r] = 0.f; a1[r] = 0.f; }
      {
        const int rb0 = l31 * 64;
        const int rb1 = (32 + l31) * 64;
        const int r7 = l31 & 7;
        __builtin_amdgcn_s_setprio(1);
#pragma unroll
        for (int m = 0; m < 4; ++m) {
          const int c = (((m << 1) | hi) ^ r7) * 8;
          bf16x8 kf0 = *(const bf16x8*)&Kb[rb0 + c];
          bf16x8 kf1 = *(const bf16x8*)&Kb[rb1 + c];
          a0 = __builtin_amdgcn_mfma_f32_32x32x16_bf16(kf0, Qf[m], a0, 0, 0, 0);
          a1 = __builtin_amdgcn_mfma_f32_32x32x16_bf16(kf1, Qf[m], a1, 0, 0, 0);
        }
        __builtin_amdgcn_s_setprio(0);
      }

      // ---- causal mask: only the diagonal-crossing tile ----
      if (kt == myBound) {
        const int qglob = q0w + l31;
#pragma unroll
        for (int r = 0; r < 16; ++r) {
          const int kvb = kt * 64 + (r & 3) + ((r >> 2) << 3) + (hi << 2);
          if (kvb > qglob) a0[r] = -INFINITY;
          if (kvb + 32 > qglob) a1[r] = -INFINITY;
        }
      }

      // ---- online softmax: tree max, defer-max (THR=8 in log2 space) ----
      float m8[8];
#pragma unroll
      for (int j = 0; j < 8; ++j)
        m8[j] = fmaxf(fmaxf(a0[j], a0[j + 8]), fmaxf(a1[j], a1[j + 8]));
      float pp = fmaxf(fmaxf(fmaxf(m8[0], m8[4]), fmaxf(m8[1], m8[5])),
                       fmaxf(fmaxf(m8[2], m8[6]), fmaxf(m8[3], m8[7])));
      float pmax;
      XHALF(pmax, pp, fmaxf);
      if (__any(pmax > m_i + 8.f)) {
        const float mnew = fmaxf(m_i, pmax);
        const float al = fast_exp2(m_i - mnew);
        m_i = mnew;
        l_i *= al;
#pragma unroll
        for (int r = 0; r < 16; ++r) { o[0][r] *= al; o[1][r] *= al; }
      }

#pragma unroll
      for (int r = 0; r < 16; ++r) {
        a0[r] = fast_exp2(a0[r] - m_i);
        a1[r] = fast_exp2(a1[r] - m_i);
      }
      float s8[8];
#pragma unroll
      for (int j = 0; j < 8; ++j)
        s8[j] = (a0[j] + a0[j + 8]) + (a1[j] + a1[j + 8]);
      float rp = ((s8[0] + s8[1]) + (s8[2] + s8[3])) +
                 ((s8[4] + s8[5]) + (s8[6] + s8[7]));
      float rs;
      XHALF(rs, rp, fadd_);
      l_i += rs;

      // ---- P^T B-fragments: cvt_pk pairs + permlane32_swap half-exchange ----
      bf16x8 Pf[4];
#pragma unroll
      for (int m = 0; m < 4; ++m) {
        const int rb2 = (m & 1) * 8;
        uint32_t u0, u1, u2, u3;
        const f32x16& s = (m >> 1) ? a1 : a0;
        asm("v_cvt_pk_bf16_f32 %0, %1, %2" : "=v"(u0) : "v"(s[rb2 + 0]), "v"(s[rb2 + 1]));
        asm("v_cvt_pk_bf16_f32 %0, %1, %2" : "=v"(u1) : "v"(s[rb2 + 2]), "v"(s[rb2 + 3]));
        asm("v_cvt_pk_bf16_f32 %0, %1, %2" : "=v"(u2) : "v"(s[rb2 + 4]), "v"(s[rb2 + 5]));
        asm("v_cvt_pk_bf16_f32 %0, %1, %2" : "=v"(u3) : "v"(s[rb2 + 6]), "v"(s[rb2 + 7]));
        asm("v_permlane32_swap_b32 %0, %1" : "+v"(u0), "+v"(u2));
        asm("v_permlane32_swap_b32 %0, %1" : "+v"(u1), "+v"(u3));
        u32x4 pw = {u0, u1, u2, u3};
        Pf[m] = __builtin_bit_cast(bf16x8, pw);
      }

      // ---- O^T += V^T P^T ----
      __builtin_amdgcn_s_setprio(1);
#pragma unroll
      for (int dt = 0; dt < 2; ++dt) {
        const int d = dt * 32 + l31;
        const int base = d * 64;
        const int dsw = ((d >> 3) ^ d) & 7;
#pragma unroll
        for (int m = 0; m < 4; ++m) {
          bf16x8 vf = *(const bf16x8*)&Vb[base + ((((m << 1) | hi) ^ dsw) & 7) * 8];
          o[dt] = __builtin_amdgcn_mfma_f32_32x32x16_bf16(vf, Pf[m], o[dt], 0, 0, 0);
        }
      }
      __builtin_amdgcn_s_setprio(0);
    }

    if (pf) VSCATTER(&Vs[cur ^ 1][0], v0, v1);
    cur ^= 1;
  }

  // ---- epilogue: normalize, pack to bf16, swap to contiguous d-runs, store ----
  const float rl = 1.0f / l_i;
#pragma unroll
  for (int dt = 0; dt < 2; ++dt) {
    float s[16];
#pragma unroll
    for (int r = 0; r < 16; ++r) s[r] = o[dt][r] * rl;
    uint32_t u[8];
#pragma unroll
    for (int p = 0; p < 8; ++p)
      asm("v_cvt_pk_bf16_f32 %0, %1, %2" : "=v"(u[p]) : "v"(s[2 * p]), "v"(s[2 * p + 1]));
    asm("v_permlane32_swap_b32 %0, %1" : "+v"(u[0]), "+v"(u[2]));
    asm("v_permlane32_swap_b32 %0, %1" : "+v"(u[1]), "+v"(u[3]));
    asm("v_permlane32_swap_b32 %0, %1" : "+v"(u[4]), "+v"(u[6]));
    asm("v_permlane32_swap_b32 %0, %1" : "+v"(u[5]), "+v"(u[7]));
    unsigned short* op =
        ob + (size_t)(b * T_ + q0w + l31) * 1024 + h * 64 + dt * 32 + hi * 8;
    u32x4 c0 = {u[0], u[1], u[2], u[3]};   // d = dt*32 + hi*8 + [0..8)
    u32x4 c1 = {u[4], u[5], u[6], u[7]};   // d = dt*32 + 16 + hi*8 + [0..8)
    *(u32x4*)op = c0;
    *(u32x4*)(op + 16) = c1;
  }
}

// ---------------- host launch ----------------
extern "C" void kernel_launch(void* const* d_in, const int* in_sizes, int n_in,
                              void* d_out, int out_size, void* d_ws,
                              size_t ws_size, hipStream_t stream) {
  const float* x = (const float*)d_in[0];
  const float* Wq = (const float*)d_in[1];
  const float* Wk = (const float*)d_in[2];
  const float* Wv = (const float*)d_in[3];
  const float* Wo = (const float*)d_in[4];
  const float* bo = (const float*)d_in[5];
  float* out = (float*)d_out;

  char* ws = (char*)d_ws;
  unsigned short* xb   = (unsigned short*)(ws + 0);          // 16 MB
  unsigned short* wqkv = (unsigned short*)(ws + 16777216);   // 6 MB
  unsigned short* wo   = (unsigned short*)(ws + 23068672);   // 2 MB
  unsigned short* qkv  = (unsigned short*)(ws + 25165824);   // 48 MB
  unsigned short* ob   = (unsigned short*)(ws + 75497472);   // 16 MB
  if (ws_size < 92274688u) return;

  cvt_all<<<12288, 256, 0, stream>>>(x, Wq, Wk, Wv, Wo, xb, wqkv, wo);

  // fused QKV projection (m97 structure, proven ~78.5us here)
  gemm_bt<0><<<dim3(NQKV / 128, MTOT / 128), 256, 0, stream>>>(
      xb, wqkv, qkv, nullptr, nullptr, 1024, NQKV);

  // causal flash attention (1024 fine-grained blocks, 4 blocks/CU)
  attn_kernel<<<dim3(1024), 256, 0, stream>>>(qkv, ob);

  // output projection + bias
  gemm_bt<1><<<dim3(1024 / 128, MTOT / 128), 256, 0, stream>>>(
      ob, wo, nullptr, out, bo, 1024, 1024);
}

// Round 8
// 170.517 us; speedup vs baseline: 1.1996x; 1.0815x over previous
//
#include <hip/hip_runtime.h>
#include <hip/hip_bf16.h>
#include <stdint.h>

// Problem constants
#define B_   4
#define T_   2048
#define H_   16
#define MTOT (B_ * T_)          // 8192 rows
#define NQKV 3072               // fused QKV output cols
#define QSC  0.18033688f        // 0.125 * log2(e): fold softmax scale + exp2 conversion into Q

typedef __attribute__((ext_vector_type(8))) __bf16 bf16x8;
typedef __attribute__((ext_vector_type(4))) float f32x4;
typedef __attribute__((ext_vector_type(16))) float f32x16;
typedef __attribute__((ext_vector_type(4))) float f4v;
typedef __attribute__((ext_vector_type(4))) unsigned short us4;
typedef __attribute__((ext_vector_type(8))) unsigned short us8;
typedef __attribute__((ext_vector_type(4))) unsigned int u32x4;

static __device__ __forceinline__ unsigned short f2bf(float f) {
  __hip_bfloat16 h = __float2bfloat16(f);
  return __builtin_bit_cast(unsigned short, h);
}

static __device__ __forceinline__ float fast_exp2(float x) {
#if __has_builtin(__builtin_amdgcn_exp2f)
  return __builtin_amdgcn_exp2f(x);
#else
  float r; asm("v_exp_f32 %0, %1" : "=v"(r) : "v"(x)); return r;
#endif
}

static __device__ __forceinline__ void async16(const void* g, void* l) {
  __builtin_amdgcn_global_load_lds(
      (const __attribute__((address_space(1))) void*)g,
      (__attribute__((address_space(3))) void*)l, 16, 0, 0);
}

// cross-half (lane ^ 32) reduce via permlane32_swap (VALU) instead of
// ds_bpermute (__shfl_xor).
#define XHALF(res, x, OP)                                  \
  {                                                        \
    float t1_ = (x), t2_ = (x);                            \
    asm("" : "+v"(t2_));                                   \
    asm("v_permlane32_swap_b32 %0, %1" : "+v"(t1_), "+v"(t2_)); \
    res = OP(t1_, t2_);                                    \
  }
static __device__ __forceinline__ float fadd_(float a, float b) { return a + b; }

// ---------------- fused fp32 -> bf16 convert (x4 vectorized, 1 launch) --------
__global__ __launch_bounds__(256) void cvt_all(
    const float* __restrict__ x, const float* __restrict__ Wq,
    const float* __restrict__ Wk, const float* __restrict__ Wv,
    const float* __restrict__ Wo, unsigned short* __restrict__ xb,
    unsigned short* __restrict__ wqkv, unsigned short* __restrict__ wo) {
  int i = blockIdx.x * blockDim.x + threadIdx.x;
  const float* s; unsigned short* d; int j;
  if (i < 2097152)      { s = x;  d = xb;             j = i; }
  else if (i < 2359296) { s = Wq; d = wqkv;           j = i - 2097152; }
  else if (i < 2621440) { s = Wk; d = wqkv + 1048576; j = i - 2359296; }
  else if (i < 2883584) { s = Wv; d = wqkv + 2097152; j = i - 2621440; }
  else                  { s = Wo; d = wo;             j = i - 2883584; }
  f4v v = reinterpret_cast<const f4v*>(s)[j];
  us4 o;
  o.x = f2bf(v.x); o.y = f2bf(v.y); o.z = f2bf(v.z); o.w = f2bf(v.w);
  reinterpret_cast<us4*>(d)[j] = o;
}

// ---------------- bf16 GEMM (m97 2-barrier structure, BK=64), C = A * B^T ----
// - BK=64: 8 barrier pairs at K=1024 (was 16); fragments read per-32K subchunk
//   inside the iter so VGPR stays ~72.
// - LDS K-slot XOR swizzle slot' = slot ^ (row&7), applied both-sides (rule 21):
//   linear global_load_lds dest + inverse-swizzled global SOURCE + swizzled
//   ds_read -> 2-way max bank aliasing (was 8-way at BK=32, would be 16-way
//   linear at BK=64).
// - XCD-chunked 1D grid (bijective, grid%8==0): each XCD owns 8 contiguous
//   m-panels (A working set 2MB -> L2-resident); NT = n-tiles in grid.
// MODE 0: bf16 out, cols<1024 scaled by QSC.  MODE 1: f32 out + bias.
template <int MODE, int NT>
__global__ __launch_bounds__(256) void gemm_bt(
    const unsigned short* __restrict__ A,   // [M][K] bf16 bits
    const unsigned short* __restrict__ Bw,  // [N][K] bf16 bits
    unsigned short* __restrict__ Cb,        // bf16 out (MODE 0)
    float* __restrict__ Cf,                 // f32 out (MODE 1)
    const float* __restrict__ bias,         // MODE 1
    int K, int N) {
  __shared__ __align__(16) unsigned short As[128 * 64];
  __shared__ __align__(16) unsigned short Bs[128 * 64];

  const int bid = blockIdx.x;
  const int xcd = bid & 7;
  const int loc = bid >> 3;
  const int m0 = (xcd * 8 + loc / NT) * 128;
  const int n0 = (loc % NT) * 128;

  const int t = threadIdx.x;
  const int lane = t & 63;
  const int w = t >> 6;
  const int lr = lane & 15;
  const int lg = lane >> 4;
  const int wm = w >> 1;
  const int wn = w & 1;

  f32x4 acc[4][4];
#pragma unroll
  for (int i = 0; i < 4; ++i)
#pragma unroll
    for (int j = 0; j < 4; ++j) acc[i][j] = (f32x4){0.f, 0.f, 0.f, 0.f};

  // staging: chunk c = k*256 + t (k=0..3): row = c>>3 (0..127), LDS slot c&7.
  // LDS slot l at row r holds global k-slot l ^ (r&7)  (inverse-swizzled src).
  const int srow = t >> 3;                       // base row (k adds 32k)
  const int gs = (t & 7) ^ ((t >> 3) & 7);       // global k-slot for this thread
  const unsigned short* ga = A + (size_t)(m0 + srow) * K + gs * 8;
  const unsigned short* gb = Bw + (size_t)(n0 + srow) * K + gs * 8;

  // read swizzle: want k-slot kk*4+lg of row (..+lr) -> LDS slot ^ (lr&7)
  const int rsw = lr & 7;

  for (int k0 = 0; k0 < K; k0 += 64) {
#pragma unroll
    for (int k = 0; k < 4; ++k) {
      async16(ga + (size_t)(k * 32) * K + k0, &As[(k * 256 + t) * 8]);
      async16(gb + (size_t)(k * 32) * K + k0, &Bs[(k * 256 + t) * 8]);
    }
    __syncthreads();

#pragma unroll
    for (int kk = 0; kk < 2; ++kk) {
      const int slot = ((kk * 4 + lg) ^ rsw) * 8;
      bf16x8 af[4], bfr[4];
#pragma unroll
      for (int mi = 0; mi < 4; ++mi)
        af[mi] = *(const bf16x8*)&As[(wm * 64 + mi * 16 + lr) * 64 + slot];
#pragma unroll
      for (int ni = 0; ni < 4; ++ni)
        bfr[ni] = *(const bf16x8*)&Bs[(wn * 64 + ni * 16 + lr) * 64 + slot];
#pragma unroll
      for (int mi = 0; mi < 4; ++mi)
#pragma unroll
        for (int ni = 0; ni < 4; ++ni)
          acc[mi][ni] = __builtin_amdgcn_mfma_f32_16x16x32_bf16(
              af[mi], bfr[ni], acc[mi][ni], 0, 0, 0);
    }
    __syncthreads();
  }

  // epilogue: D layout col=lane&15, row=(lane>>4)*4+r
#pragma unroll
  for (int mi = 0; mi < 4; ++mi) {
    const int row = m0 + wm * 64 + mi * 16 + lg * 4;
#pragma unroll
    for (int ni = 0; ni < 4; ++ni) {
      const int col = n0 + wn * 64 + ni * 16 + lr;
#pragma unroll
      for (int r = 0; r < 4; ++r) {
        if (MODE == 1) {
          Cf[(size_t)(row + r) * N + col] = acc[mi][ni][r] + bias[col];
        } else {
          float v = acc[mi][ni][r];
          if (col < 1024) v *= QSC;   // pre-scale Q for exp2-space softmax
          Cb[(size_t)(row + r) * N + col] = f2bf(v);
        }
      }
    }
  }
}

// ---------------- causal flash attention (4 waves x 32 q-rows, 32x32 MFMA) ----
// qkv: [8192][3072] bf16 (cols: 0..1023 Q (pre-scaled), 1024..2047 K, 2048..3071 V)
// ob : [8192][1024] bf16 attention output (col = h*64+d)
//
// 1024 blocks = 64 (b,h) pairs x 16 q-groups of 128 rows; 4 waves x 32 q-rows.
// KVBLK=64, 32KB LDS -> 4 blocks/CU, whole grid co-resident; snake qg mapping
// makes per-CU work sums constant.
__global__ __launch_bounds__(256, 4) void attn_kernel(
    const unsigned short* __restrict__ qkv, unsigned short* __restrict__ ob) {
  const int bid = blockIdx.x;
  const int pair = bid & 63;
  const int g = bid >> 6;               // 0..15, dispatch round-major
  const int rnd = g >> 2, idx = g & 3;
  const int qg = (rnd == 0) ? (15 - idx)
               : (rnd == 1) ? (8 + idx)
               : (rnd == 2) ? (7 - idx) : idx;   // CU sums constant
  const int b = pair >> 4;
  const int h = pair & 15;
  const int t = threadIdx.x;
  const int w = t >> 6;                 // 0..3
  const int lane = t & 63;
  const int l31 = lane & 31;
  const int hi = lane >> 5;

  const int q0w = qg * 128 + w * 32;       // wave's q strip
  const int myBound = 2 * qg + (w >> 1);   // last kv-tile this wave computes
  const int NT = 2 * qg + 2;               // 64-row kv tiles staged by block

  __shared__ __align__(16) unsigned short Ks[2][64 * 64];
  __shared__ __align__(16) unsigned short Vs[2][64 * 64];   // V^T [d][kv], swizzled

  const size_t rowbase = (size_t)(b * T_) * NQKV;

  // ---- Q B-fragments: col=q=l31, k=d = m*16 + hi*8 + i ----
  bf16x8 Qf[4];
  {
    const unsigned short* qp =
        qkv + rowbase + (size_t)(q0w + l31) * NQKV + h * 64 + hi * 8;
#pragma unroll
    for (int m = 0; m < 4; ++m) Qf[m] = *(const bf16x8*)(qp + m * 16);
  }

  // ---- staging geometry (256 threads) ----
  const int kr = t >> 3;                // 0..31
  const int ks = t & 7;
  const unsigned short* kbase =
      qkv + rowbase + 1024 + h * 64 + (ks ^ (kr & 7)) * 8 + (size_t)kr * NQKV;
  const int kvr = t >> 2;               // 0..63
  const int dc2 = (t & 3) * 2;
  const unsigned short* vbase =
      qkv + rowbase + 2048 + h * 64 + dc2 * 8 + (size_t)kvr * NQKV;

  float m_i = -INFINITY, l_i = 0.f;
  f32x16 o[2];
#pragma unroll
  for (int r = 0; r < 16; ++r) { o[0][r] = 0.f; o[1][r] = 0.f; }

#define VSCATTER(Vb, v0, v1)                                       \
  {                                                                \
    _Pragma("unroll") for (int i = 0; i < 8; ++i) {                \
      const int s0 = ((kvr >> 3) ^ dc2 ^ i) & 7;                   \
      const int s1 = ((kvr >> 3) ^ (dc2 + 1) ^ i) & 7;             \
      (Vb)[(dc2 * 8 + i) * 64 + s0 * 8 + (kvr & 7)] = (v0)[i];     \
      (Vb)[((dc2 + 1) * 8 + i) * 64 + s1 * 8 + (kvr & 7)] = (v1)[i]; \
    }                                                              \
  }

  // ---- prologue: stage tile 0 into buffer 0 ----
  {
    async16(kbase, &Ks[0][t * 8]);
    async16(kbase + (size_t)32 * NQKV, &Ks[0][2048 + t * 8]);
    us8 v0 = *(const us8*)vbase;
    us8 v1 = *(const us8*)(vbase + 8);
    VSCATTER(&Vs[0][0], v0, v1);
  }

  int cur = 0;
  for (int kt = 0; kt < NT; ++kt) {
    __syncthreads();  // buf[cur] ready (drains async K + V ds_writes)

    const bool pf = (kt + 1 < NT);
    us8 v0, v1;
    if (pf) {
      const size_t off = (size_t)(kt + 1) * 64 * NQKV;
      async16(kbase + off, &Ks[cur ^ 1][t * 8]);
      async16(kbase + off + (size_t)32 * NQKV, &Ks[cur ^ 1][2048 + t * 8]);
      v0 = *(const us8*)(vbase + off);
      v1 = *(const us8*)(vbase + off + 8);
    }

    if (kt <= myBound) {
      const unsigned short* Kb = Ks[cur];
      const unsigned short* Vb = Vs[cur];

      // ---- S^T[kv][q] : 2 kv-subtiles of 32 ----
      f32x16 a0, a1;
#pragma unroll
      for (int r = 0; r < 16; ++r) { a0[r] = 0.f; a1[r] = 0.f; }
      {
        const int rb0 = l31 * 64;
        const int rb1 = (32 + l31) * 64;
        const int r7 = l31 & 7;
        __builtin_amdgcn_s_setprio(1);
#pragma unroll
        for (int m = 0; m < 4; ++m) {
          const int c = (((m << 1) | hi) ^ r7) * 8;
          bf16x8 kf0 = *(const bf16x8*)&Kb[rb0 + c];
          bf16x8 kf1 = *(const bf16x8*)&Kb[rb1 + c];
          a0 = __builtin_amdgcn_mfma_f32_32x32x16_bf16(kf0, Qf[m], a0, 0, 0, 0);
          a1 = __builtin_amdgcn_mfma_f32_32x32x16_bf16(kf1, Qf[m], a1, 0, 0, 0);
        }
        __builtin_amdgcn_s_setprio(0);
      }

      // ---- causal mask: only the diagonal-crossing tile ----
      if (kt == myBound) {
        const int qglob = q0w + l31;
#pragma unroll
        for (int r = 0; r < 16; ++r) {
          const int kvb = kt * 64 + (r & 3) + ((r >> 2) << 3) + (hi << 2);
          if (kvb > qglob) a0[r] = -INFINITY;
          if (kvb + 32 > qglob) a1[r] = -INFINITY;
        }
      }

      // ---- online softmax: tree max, defer-max (THR=8 in log2 space) ----
      float m8[8];
#pragma unroll
      for (int j = 0; j < 8; ++j)
        m8[j] = fmaxf(fmaxf(a0[j], a0[j + 8]), fmaxf(a1[j], a1[j + 8]));
      float pp = fmaxf(fmaxf(fmaxf(m8[0], m8[4]), fmaxf(m8[1], m8[5])),
                       fmaxf(fmaxf(m8[2], m8[6]), fmaxf(m8[3], m8[7])));
      float pmax;
      XHALF(pmax, pp, fmaxf);
      if (__any(pmax > m_i + 8.f)) {
        const float mnew = fmaxf(m_i, pmax);
        const float al = fast_exp2(m_i - mnew);
        m_i = mnew;
        l_i *= al;
#pragma unroll
        for (int r = 0; r < 16; ++r) { o[0][r] *= al; o[1][r] *= al; }
      }

#pragma unroll
      for (int r = 0; r < 16; ++r) {
        a0[r] = fast_exp2(a0[r] - m_i);
        a1[r] = fast_exp2(a1[r] - m_i);
      }
      float s8[8];
#pragma unroll
      for (int j = 0; j < 8; ++j)
        s8[j] = (a0[j] + a0[j + 8]) + (a1[j] + a1[j + 8]);
      float rp = ((s8[0] + s8[1]) + (s8[2] + s8[3])) +
                 ((s8[4] + s8[5]) + (s8[6] + s8[7]));
      float rs;
      XHALF(rs, rp, fadd_);
      l_i += rs;

      // ---- P^T B-fragments: cvt_pk pairs + permlane32_swap half-exchange ----
      bf16x8 Pf[4];
#pragma unroll
      for (int m = 0; m < 4; ++m) {
        const int rb2 = (m & 1) * 8;
        uint32_t u0, u1, u2, u3;
        const f32x16& s = (m >> 1) ? a1 : a0;
        asm("v_cvt_pk_bf16_f32 %0, %1, %2" : "=v"(u0) : "v"(s[rb2 + 0]), "v"(s[rb2 + 1]));
        asm("v_cvt_pk_bf16_f32 %0, %1, %2" : "=v"(u1) : "v"(s[rb2 + 2]), "v"(s[rb2 + 3]));
        asm("v_cvt_pk_bf16_f32 %0, %1, %2" : "=v"(u2) : "v"(s[rb2 + 4]), "v"(s[rb2 + 5]));
        asm("v_cvt_pk_bf16_f32 %0, %1, %2" : "=v"(u3) : "v"(s[rb2 + 6]), "v"(s[rb2 + 7]));
        asm("v_permlane32_swap_b32 %0, %1" : "+v"(u0), "+v"(u2));
        asm("v_permlane32_swap_b32 %0, %1" : "+v"(u1), "+v"(u3));
        u32x4 pw = {u0, u1, u2, u3};
        Pf[m] = __builtin_bit_cast(bf16x8, pw);
      }

      // ---- O^T += V^T P^T ----
      __builtin_amdgcn_s_setprio(1);
#pragma unroll
      for (int dt = 0; dt < 2; ++dt) {
        const int d = dt * 32 + l31;
        const int base = d * 64;
        const int dsw = ((d >> 3) ^ d) & 7;
#pragma unroll
        for (int m = 0; m < 4; ++m) {
          bf16x8 vf = *(const bf16x8*)&Vb[base + ((((m << 1) | hi) ^ dsw) & 7) * 8];
          o[dt] = __builtin_amdgcn_mfma_f32_32x32x16_bf16(vf, Pf[m], o[dt], 0, 0, 0);
        }
      }
      __builtin_amdgcn_s_setprio(0);
    }

    if (pf) VSCATTER(&Vs[cur ^ 1][0], v0, v1);
    cur ^= 1;
  }

  // ---- epilogue: normalize, pack to bf16, swap to contiguous d-runs, store ----
  const float rl = 1.0f / l_i;
#pragma unroll
  for (int dt = 0; dt < 2; ++dt) {
    float s[16];
#pragma unroll
    for (int r = 0; r < 16; ++r) s[r] = o[dt][r] * rl;
    uint32_t u[8];
#pragma unroll
    for (int p = 0; p < 8; ++p)
      asm("v_cvt_pk_bf16_f32 %0, %1, %2" : "=v"(u[p]) : "v"(s[2 * p]), "v"(s[2 * p + 1]));
    asm("v_permlane32_swap_b32 %0, %1" : "+v"(u[0]), "+v"(u[2]));
    asm("v_permlane32_swap_b32 %0, %1" : "+v"(u[1]), "+v"(u[3]));
    asm("v_permlane32_swap_b32 %0, %1" : "+v"(u[4]), "+v"(u[6]));
    asm("v_permlane32_swap_b32 %0, %1" : "+v"(u[5]), "+v"(u[7]));
    unsigned short* op =
        ob + (size_t)(b * T_ + q0w + l31) * 1024 + h * 64 + dt * 32 + hi * 8;
    u32x4 c0 = {u[0], u[1], u[2], u[3]};   // d = dt*32 + hi*8 + [0..8)
    u32x4 c1 = {u[4], u[5], u[6], u[7]};   // d = dt*32 + 16 + hi*8 + [0..8)
    *(u32x4*)op = c0;
    *(u32x4*)(op + 16) = c1;
  }
}

// ---------------- host launch ----------------
extern "C" void kernel_launch(void* const* d_in, const int* in_sizes, int n_in,
                              void* d_out, int out_size, void* d_ws,
                              size_t ws_size, hipStream_t stream) {
  const float* x = (const float*)d_in[0];
  const float* Wq = (const float*)d_in[1];
  const float* Wk = (const float*)d_in[2];
  const float* Wv = (const float*)d_in[3];
  const float* Wo = (const float*)d_in[4];
  const float* bo = (const float*)d_in[5];
  float* out = (float*)d_out;

  char* ws = (char*)d_ws;
  unsigned short* xb   = (unsigned short*)(ws + 0);          // 16 MB
  unsigned short* wqkv = (unsigned short*)(ws + 16777216);   // 6 MB
  unsigned short* wo   = (unsigned short*)(ws + 23068672);   // 2 MB
  unsigned short* qkv  = (unsigned short*)(ws + 25165824);   // 48 MB
  unsigned short* ob   = (unsigned short*)(ws + 75497472);   // 16 MB
  if (ws_size < 92274688u) return;

  cvt_all<<<12288, 256, 0, stream>>>(x, Wq, Wk, Wv, Wo, xb, wqkv, wo);

  // fused QKV projection: BK=64, both-sides swizzle, XCD m-chunked grid
  // (1536 blocks = 8 XCDs x (8 m-panels x 24 n-tiles))
  gemm_bt<0, 24><<<1536, 256, 0, stream>>>(
      xb, wqkv, qkv, nullptr, nullptr, 1024, NQKV);

  // causal flash attention (1024 fine-grained blocks, 4 blocks/CU)
  attn_kernel<<<dim3(1024), 256, 0, stream>>>(qkv, ob);

  // output projection + bias (512 blocks = 8 XCDs x (8 m-panels x 8 n-tiles))
  gemm_bt<1, 8><<<512, 256, 0, stream>>>(
      ob, wo, nullptr, out, bo, 1024, 1024);
}